// Round 11
// baseline (2531.426 us; speedup 1.0000x reference)
//
#include <hip/hip_runtime.h>
#include <hip/hip_fp16.h>

#define B_ 64
#define M_ 512
#define N_ 512
#define D_ 128
constexpr float EPS_ = 0.05f;
constexpr float SHIFT_ = 1.25f;  // K' = exp((SHIFT - D)/EPS) fits fp8 e4m3 [~2e-3 .. 448]
constexpr int NIT_ = 200;

typedef _Float16 h2 __attribute__((ext_vector_type(2)));
typedef float f2 __attribute__((ext_vector_type(2)));

__device__ __forceinline__ unsigned h2u(h2 x) { return __builtin_bit_cast(unsigned, x); }
__device__ __forceinline__ h2 u2h(unsigned x) { return __builtin_bit_cast(h2, x); }

template <bool HI>
__device__ __forceinline__ h2 cvt_h2(unsigned w) {
#if __has_builtin(__builtin_amdgcn_cvt_scalef32_pk_f16_fp8)
    return __builtin_bit_cast(h2, __builtin_amdgcn_cvt_scalef32_pk_f16_fp8(w, 1.0f, HI));
#else
    f2 f = __builtin_amdgcn_cvt_pk_f32_fp8((int)w, HI);
    return __builtin_bit_cast(h2, __builtin_amdgcn_cvt_pkrtz(f.x, f.y));
#endif
}
template <bool HI>
__device__ __forceinline__ f2 cvt_f2(unsigned w) {
    return __builtin_amdgcn_cvt_pk_f32_fp8((int)w, HI);
}

__device__ __forceinline__ float dot2f(h2 a, h2 b, float c) {
#if __has_builtin(__builtin_amdgcn_fdot2)
    return __builtin_amdgcn_fdot2(a, b, c, false);
#else
    return fmaf((float)a.x, (float)b.x, fmaf((float)a.y, (float)b.y, c));
#endif
}

// sum across each 16-lane group via DPP (VALU only); all 16 lanes get the sum
__device__ __forceinline__ float red16(float x) {
    x += __builtin_bit_cast(float, __builtin_amdgcn_mov_dpp(__builtin_bit_cast(int, x), 0xB1, 0xF, 0xF, true));  // quad_perm xor1
    x += __builtin_bit_cast(float, __builtin_amdgcn_mov_dpp(__builtin_bit_cast(int, x), 0x4E, 0xF, 0xF, true));  // quad_perm xor2
    x += __builtin_bit_cast(float, __builtin_amdgcn_mov_dpp(__builtin_bit_cast(int, x), 0x124, 0xF, 0xF, true)); // row_ror:4
    x += __builtin_bit_cast(float, __builtin_amdgcn_mov_dpp(__builtin_bit_cast(int, x), 0x128, 0xF, 0xF, true)); // row_ror:8
    return x;
}

__device__ __forceinline__ h2 padd(h2 a, h2 b) { return a + b; }

// ---------------------------------------------------------------------------
__global__ __launch_bounds__(256) void wmd_norms(const float* __restrict__ x,
                                                 const float* __restrict__ y,
                                                 float* __restrict__ xn,
                                                 float* __restrict__ yn) {
    int gw = (int)((blockIdx.x * blockDim.x + threadIdx.x) >> 6);
    int l = threadIdx.x & 63;
    const float* src; float* dst; int row;
    if (gw < B_ * M_) { src = x; dst = xn; row = gw; }
    else              { src = y; dst = yn; row = gw - B_ * M_; }
    float2 a = ((const float2*)(src + (size_t)row * D_))[l];
    float s = a.x * a.x + a.y * a.y;
#pragma unroll
    for (int off = 32; off; off >>= 1) s += __shfl_xor(s, off);
    if (l == 0) dst[row] = s;
}

// ---------------------------------------------------------------------------
// K'[b,i,j] = clamp(exp((SHIFT - D_ij)/EPS), 448) in fp8 e4m3, written SPLIT:
//   KL[b][row][c]      c = cols 0..255   (staged to LDS by sinkhorn)
//   KR[b][row][c-256]  c = cols 256..511 (streamed from L2 by sinkhorn)
__global__ __launch_bounds__(256) void wmd_build_k(const float* __restrict__ x,
                                                   const float* __restrict__ y,
                                                   const float* __restrict__ xn,
                                                   const float* __restrict__ yn,
                                                   unsigned char* __restrict__ KL,
                                                   unsigned char* __restrict__ KR) {
    int b = blockIdx.z, it = blockIdx.y, jt = blockIdx.x;
    __shared__ float xs[32][129];
    __shared__ float ys[32][129];
    const float4* xb = (const float4*)(x + ((size_t)b * M_ + it * 32) * D_);
    const float4* yb = (const float4*)(y + ((size_t)b * N_ + jt * 32) * D_);
    int t = threadIdx.x;
#pragma unroll
    for (int k = 0; k < 4; ++k) {
        int idx = t + k * 256;
        int r = idx >> 5, c = (idx & 31) * 4;
        float4 vx = xb[idx];
        float4 vy = yb[idx];
        xs[r][c] = vx.x; xs[r][c + 1] = vx.y; xs[r][c + 2] = vx.z; xs[r][c + 3] = vx.w;
        ys[r][c] = vy.x; ys[r][c + 1] = vy.y; ys[r][c + 2] = vy.z; ys[r][c + 3] = vy.w;
    }
    __syncthreads();
    int ti = t >> 5, tj = t & 31;
    float a0 = 0.f, a1 = 0.f, a2 = 0.f, a3 = 0.f;
    for (int d = 0; d < D_; ++d) {
        float yv = ys[tj][d];
        a0 += xs[ti][d] * yv;
        a1 += xs[ti + 8][d] * yv;
        a2 += xs[ti + 16][d] * yv;
        a3 += xs[ti + 24][d] * yv;
    }
    float ynj = yn[(size_t)b * N_ + jt * 32 + tj];
    float accs[4] = {a0, a1, a2, a3};
    unsigned char* dst = (jt < 8) ? KL : KR;
    int cj = (jt & 7) * 32 + tj;
#pragma unroll
    for (int k = 0; k < 4; ++k) {
        int gi = it * 32 + ti + 8 * k;
        float sq = (xn[(size_t)b * M_ + gi] + ynj - 2.0f * accs[k]) * (1.0f / D_);
        float Dv = sqrtf(fmaxf(sq, 1e-12f));
        float kv = fminf(expf((SHIFT_ - Dv) * (1.0f / EPS_)), 448.0f);
        unsigned r8 = (unsigned)__builtin_amdgcn_cvt_pk_fp8_f32(kv, kv, 0, false);
        dst[((size_t)b * M_ + gi) * 256 + cj] = (unsigned char)(r8 & 0xff);
    }
}

// ---------------------------------------------------------------------------
// Persistent Sinkhorn: 1 WG (8 waves, 512 thr) per batch.
// K residency by COLUMN half (no persistent K registers -> live set ~70 << 128
// grant, no spill):  cols 0..255 in LDS (131 KiB, row stride 272 B);
// cols 256..511 streamed from L2 via a 2-group-deep static prefetch ring.
// Lane l: sub = l&15 owns scalar cols [sub*32, +32); sub<8 lanes read LDS,
// sub>=8 lanes read L2. rg = l>>4; wave w owns rows w*64 + g*4 + rg, g=0..15.
__global__ __attribute__((amdgpu_flat_work_group_size(512, 512)))
void wmd_sinkhorn(const unsigned char* __restrict__ KL,
                  const unsigned char* __restrict__ KR,
                  float* __restrict__ wmd) {
    int b = blockIdx.x;
    __shared__ uint4 kld4[512 * 17];  // 512 rows x 256 fp8, stride 17 uint4 (272 B)
    __shared__ uint4 mrg4[8 * 66];    // 8 wave-partial rows x 64 uint4 (+2 pad)
    __shared__ uint4 v_sh4[64];       // v: 256 h2 packed
    __shared__ float u_s[M_];
    __shared__ float wsum[8];
    int t = threadIdx.x, w = t >> 6, l = t & 63;
    int sub = l & 15, rg = l >> 4;
    const float pmarg = 1.0f / M_;
    const unsigned char* KLb = KL + (size_t)b * M_ * 256;
    const unsigned char* KRb = KR + (size_t)b * M_ * 256;

    // ---- stage LDS half: 8192 uint4, 512 threads x 16 (coalesced, 2-way bank ok)
#pragma unroll
    for (int k = 0; k < 16; ++k) {
        int i = t + k * 512;
        int row = i >> 4, col = i & 15;
        kld4[row * 17 + col] = ((const uint4*)KLb)[i];
    }
    __syncthreads();

    // per-lane L2 base (valid for all lanes; only used when sub>=8)
    const uint4* grow = (const uint4*)KRb + (size_t)(w * 64 + rg) * 16
                      + (sub >= 8 ? (size_t)(sub - 8) * 2 : 0);

    // load group gg's two uint4 for this lane (LDS or L2 depending on sub)
#define LOADG(P0, P1, gg)                                                      \
    if (sub < 8) {                                                             \
        int lb = (w * 64 + (gg) * 4 + rg) * 17 + sub * 2;                      \
        P0 = kld4[lb]; P1 = kld4[lb + 1];                                      \
    } else {                                                                   \
        P0 = grow[(gg) * 64]; P1 = grow[(gg) * 64 + 1];                        \
    }

    h2 vh[16];
    _Float16 one = (_Float16)1.0f;
#pragma unroll
    for (int j = 0; j < 16; ++j) vh[j] = (h2){one, one};  // v0 = 1

#pragma unroll 1
    for (int it = 0; it < NIT_; ++it) {
        h2 ca[16];
        _Float16 z = (_Float16)0.0f;
#pragma unroll
        for (int j = 0; j < 16; ++j) ca[j] = (h2){z, z};

        uint4 pA0, pA1, pB0, pB1;
        LOADG(pA0, pA1, 0);
        LOADG(pB0, pB1, 1);

#define COMPUTE(gg, A, Q)                                                      \
    {                                                                          \
        const unsigned* dwa = (const unsigned*)&(A);                           \
        const unsigned* dwq = (const unsigned*)&(Q);                           \
        float d0 = 0.f, d1 = 0.f, d2 = 0.f, d3 = 0.f;                          \
        _Pragma("unroll")                                                      \
        for (int dd = 0; dd < 4; ++dd) {                                       \
            d0 = dot2f(cvt_h2<false>(dwa[dd]), vh[2 * dd], d0);                \
            d1 = dot2f(cvt_h2<true>(dwa[dd]),  vh[2 * dd + 1], d1);            \
            d2 = dot2f(cvt_h2<false>(dwq[dd]), vh[8 + 2 * dd], d2);            \
            d3 = dot2f(cvt_h2<true>(dwq[dd]),  vh[8 + 2 * dd + 1], d3);        \
        }                                                                      \
        float dot = red16((d0 + d1) + (d2 + d3));                              \
        float rd = __builtin_amdgcn_rcpf(dot);                                 \
        if (sub == 0) u_s[w * 64 + (gg) * 4 + rg] = rd;                        \
        _Float16 uf = (_Float16)rd;                                            \
        h2 uh = (h2){uf, uf};                                                  \
        _Pragma("unroll")                                                      \
        for (int dd = 0; dd < 4; ++dd) {                                       \
            ca[2 * dd]         = cvt_h2<false>(dwa[dd]) * uh + ca[2 * dd];     \
            ca[2 * dd + 1]     = cvt_h2<true>(dwa[dd])  * uh + ca[2 * dd + 1]; \
            ca[8 + 2 * dd]     = cvt_h2<false>(dwq[dd]) * uh + ca[8 + 2 * dd]; \
            ca[8 + 2 * dd + 1] = cvt_h2<true>(dwq[dd])  * uh + ca[8 + 2 * dd + 1]; \
        }                                                                      \
    }

#pragma unroll
        for (int gp = 0; gp < 8; ++gp) {
            uint4 a0 = pA0, a1 = pA1;
            if (gp < 7) { LOADG(pA0, pA1, 2 * gp + 2); }
            COMPUTE(2 * gp, a0, a1);
            uint4 b0 = pB0, b1 = pB1;
            if (gp < 7) { LOADG(pB0, pB1, 2 * gp + 3); }
            COMPUTE(2 * gp + 1, b0, b1);
        }

        // merge the 4 rg-partials in-register: rg==0 lanes hold wave totals
#pragma unroll
        for (int j = 0; j < 16; ++j) {
            ca[j] = ca[j] + u2h((unsigned)__shfl_xor((int)h2u(ca[j]), 16));
            ca[j] = ca[j] + u2h((unsigned)__shfl_xor((int)h2u(ca[j]), 32));
        }
        if (rg == 0) {
#pragma unroll
            for (int c = 0; c < 4; ++c) {
                uint4 pk = {h2u(ca[4 * c]), h2u(ca[4 * c + 1]), h2u(ca[4 * c + 2]), h2u(ca[4 * c + 3])};
                mrg4[w * 66 + sub * 4 + c] = pk;
            }
        }
        __syncthreads();
        // column merge: task = (col-group cg of 4 h2, wave-row r). 512 tasks.
        {
            int cg = t >> 3, r = t & 7;
            uint4 s4 = mrg4[r * 66 + cg];
            h2 s0 = u2h(s4.x), s1 = u2h(s4.y), s2 = u2h(s4.z), s3 = u2h(s4.w);
#pragma unroll
            for (int d = 1; d < 8; d <<= 1) {
                s0 = padd(s0, u2h((unsigned)__shfl_xor((int)h2u(s0), d)));
                s1 = padd(s1, u2h((unsigned)__shfl_xor((int)h2u(s1), d)));
                s2 = padd(s2, u2h((unsigned)__shfl_xor((int)h2u(s2), d)));
                s3 = padd(s3, u2h((unsigned)__shfl_xor((int)h2u(s3), d)));
            }
            if (r == 0) {
                h2 r0, r1, r2, r3;
                r0.x = (_Float16)__builtin_amdgcn_rcpf((float)s0.x);
                r0.y = (_Float16)__builtin_amdgcn_rcpf((float)s0.y);
                r1.x = (_Float16)__builtin_amdgcn_rcpf((float)s1.x);
                r1.y = (_Float16)__builtin_amdgcn_rcpf((float)s1.y);
                r2.x = (_Float16)__builtin_amdgcn_rcpf((float)s2.x);
                r2.y = (_Float16)__builtin_amdgcn_rcpf((float)s2.y);
                r3.x = (_Float16)__builtin_amdgcn_rcpf((float)s3.x);
                r3.y = (_Float16)__builtin_amdgcn_rcpf((float)s3.y);
                uint4 vv = {h2u(r0), h2u(r1), h2u(r2), h2u(r3)};
                v_sh4[cg] = vv;   // v = rcp(colsum_scaled)
            }
        }
        __syncthreads();
#pragma unroll
        for (int q = 0; q < 4; ++q) {
            uint4 vv = v_sh4[sub * 4 + q];
            vh[q * 4 + 0] = u2h(vv.x);
            vh[q * 4 + 1] = u2h(vv.y);
            vh[q * 4 + 2] = u2h(vv.z);
            vh[q * 4 + 3] = u2h(vv.w);
        }
    }

    // Final: wmd_b = sum_ij u_i K_ij v_j * D_ij, D_ij = SHIFT - EPS*ln(K_ij)
    float acc = 0.f;
#pragma unroll
    for (int g = 0; g < 16; ++g) {
        uint4 a, q;
        LOADG(a, q, g);
        float us = u_s[w * 64 + g * 4 + rg];
        const unsigned* dwa = (const unsigned*)&a;
        const unsigned* dwq = (const unsigned*)&q;
#pragma unroll
        for (int dd = 0; dd < 4; ++dd) {
#pragma unroll
            for (int half = 0; half < 2; ++half) {
                unsigned word = half ? dwq[dd] : dwa[dd];
                f2 klo = cvt_f2<false>(word);
                f2 khi = cvt_f2<true>(word);
                int jb = half * 8 + dd * 2;
                h2 v0 = vh[jb], v1 = vh[jb + 1];
                float kx = fmaxf(klo.x, 1e-9f), ky = fmaxf(klo.y, 1e-9f);
                acc += (us * kx * (float)v0.x) * (SHIFT_ - EPS_ * __logf(kx));
                acc += (us * ky * (float)v0.y) * (SHIFT_ - EPS_ * __logf(ky));
                kx = fmaxf(khi.x, 1e-9f); ky = fmaxf(khi.y, 1e-9f);
                acc += (us * kx * (float)v1.x) * (SHIFT_ - EPS_ * __logf(kx));
                acc += (us * ky * (float)v1.y) * (SHIFT_ - EPS_ * __logf(ky));
            }
        }
    }
#pragma unroll
    for (int off = 1; off < 64; off <<= 1) acc += __shfl_xor(acc, off);
    if (l == 0) wsum[w] = acc;
    __syncthreads();
    if (t == 0) {
        float s = 0.f;
#pragma unroll
        for (int ww = 0; ww < 8; ++ww) s += wsum[ww];
        wmd[b] = s * pmarg;
    }
#undef LOADG
#undef COMPUTE
}

// ---------------------------------------------------------------------------
__global__ void wmd_mse(const float* __restrict__ wmd, const float* __restrict__ labels,
                        float* __restrict__ out) {
    int l = threadIdx.x;
    float d = wmd[l] - labels[l];
    d = d * d;
#pragma unroll
    for (int off = 32; off; off >>= 1) d += __shfl_xor(d, off);
    if (l == 0) out[0] = d * (1.0f / B_);
}

// ---------------------------------------------------------------------------
extern "C" void kernel_launch(void* const* d_in, const int* in_sizes, int n_in,
                              void* d_out, int out_size, void* d_ws, size_t ws_size,
                              hipStream_t stream) {
    const float* x = (const float*)d_in[0];
    const float* y = (const float*)d_in[1];
    const float* labels = (const float*)d_in[2];
    float* out = (float*)d_out;

    char* ws = (char*)d_ws;
    unsigned char* KL = (unsigned char*)ws;                             // 8 MiB
    unsigned char* KR = KL + (size_t)B_ * M_ * 256;                     // 8 MiB
    size_t off = (size_t)B_ * M_ * N_;
    float* xn = (float*)(ws + off);        off += (size_t)B_ * M_ * sizeof(float);
    float* yn = (float*)(ws + off);        off += (size_t)B_ * N_ * sizeof(float);
    float* wmd = (float*)(ws + off);

    wmd_norms<<<(B_ * (M_ + N_)) / 4, 256, 0, stream>>>(x, y, xn, yn);
    wmd_build_k<<<dim3(N_ / 32, M_ / 32, B_), 256, 0, stream>>>(x, y, xn, yn, KL, KR);
    wmd_sinkhorn<<<B_, 512, 0, stream>>>(KL, KR, wmd);
    wmd_mse<<<1, 64, 0, stream>>>(wmd, labels, out);
}

// Round 12
// 1909.166 us; speedup vs baseline: 1.3259x; 1.3259x over previous
//
#include <hip/hip_runtime.h>
#include <hip/hip_fp16.h>

#define B_ 64
#define M_ 512
#define N_ 512
#define D_ 128
constexpr float EPS_ = 0.05f;
constexpr float SHIFT_ = 1.25f;  // K' = exp((SHIFT - D)/EPS) fits fp8 e4m3 [~2e-3 .. 448]
constexpr int NIT_ = 200;

typedef _Float16 h2 __attribute__((ext_vector_type(2)));
typedef float f2 __attribute__((ext_vector_type(2)));

__device__ __forceinline__ unsigned h2u(h2 x) { return __builtin_bit_cast(unsigned, x); }
__device__ __forceinline__ h2 u2h(unsigned x) { return __builtin_bit_cast(h2, x); }

template <bool HI>
__device__ __forceinline__ h2 cvt_h2(unsigned w) {
#if __has_builtin(__builtin_amdgcn_cvt_scalef32_pk_f16_fp8)
    return __builtin_bit_cast(h2, __builtin_amdgcn_cvt_scalef32_pk_f16_fp8(w, 1.0f, HI));
#else
    f2 f = __builtin_amdgcn_cvt_pk_f32_fp8((int)w, HI);
    return __builtin_bit_cast(h2, __builtin_amdgcn_cvt_pkrtz(f.x, f.y));
#endif
}
template <bool HI>
__device__ __forceinline__ f2 cvt_f2(unsigned w) {
    return __builtin_amdgcn_cvt_pk_f32_fp8((int)w, HI);
}

__device__ __forceinline__ float dot2f(h2 a, h2 b, float c) {
#if __has_builtin(__builtin_amdgcn_fdot2)
    return __builtin_amdgcn_fdot2(a, b, c, false);
#else
    return fmaf((float)a.x, (float)b.x, fmaf((float)a.y, (float)b.y, c));
#endif
}

// sum across each 16-lane group via DPP (VALU only); all 16 lanes get the sum
__device__ __forceinline__ float red16(float x) {
    x += __builtin_bit_cast(float, __builtin_amdgcn_mov_dpp(__builtin_bit_cast(int, x), 0xB1, 0xF, 0xF, true));  // quad_perm xor1
    x += __builtin_bit_cast(float, __builtin_amdgcn_mov_dpp(__builtin_bit_cast(int, x), 0x4E, 0xF, 0xF, true));  // quad_perm xor2
    x += __builtin_bit_cast(float, __builtin_amdgcn_mov_dpp(__builtin_bit_cast(int, x), 0x124, 0xF, 0xF, true)); // row_ror:4
    x += __builtin_bit_cast(float, __builtin_amdgcn_mov_dpp(__builtin_bit_cast(int, x), 0x128, 0xF, 0xF, true)); // row_ror:8
    return x;
}

// ---------------------------------------------------------------------------
__global__ __launch_bounds__(256) void wmd_norms(const float* __restrict__ x,
                                                 const float* __restrict__ y,
                                                 float* __restrict__ xn,
                                                 float* __restrict__ yn) {
    int gw = (int)((blockIdx.x * blockDim.x + threadIdx.x) >> 6);
    int l = threadIdx.x & 63;
    const float* src; float* dst; int row;
    if (gw < B_ * M_) { src = x; dst = xn; row = gw; }
    else              { src = y; dst = yn; row = gw - B_ * M_; }
    float2 a = ((const float2*)(src + (size_t)row * D_))[l];
    float s = a.x * a.x + a.y * a.y;
#pragma unroll
    for (int off = 32; off; off >>= 1) s += __shfl_xor(s, off);
    if (l == 0) dst[row] = s;
}

// ---------------------------------------------------------------------------
// K'[b,i,j] = clamp(exp((SHIFT - D_ij)/EPS), 448) in fp8 e4m3 (contiguous)
__global__ __launch_bounds__(256) void wmd_build_k(const float* __restrict__ x,
                                                   const float* __restrict__ y,
                                                   const float* __restrict__ xn,
                                                   const float* __restrict__ yn,
                                                   unsigned char* __restrict__ Kp) {
    int b = blockIdx.z, it = blockIdx.y, jt = blockIdx.x;
    __shared__ float xs[32][129];
    __shared__ float ys[32][129];
    const float4* xb = (const float4*)(x + ((size_t)b * M_ + it * 32) * D_);
    const float4* yb = (const float4*)(y + ((size_t)b * N_ + jt * 32) * D_);
    int t = threadIdx.x;
#pragma unroll
    for (int k = 0; k < 4; ++k) {
        int idx = t + k * 256;
        int r = idx >> 5, c = (idx & 31) * 4;
        float4 vx = xb[idx];
        float4 vy = yb[idx];
        xs[r][c] = vx.x; xs[r][c + 1] = vx.y; xs[r][c + 2] = vx.z; xs[r][c + 3] = vx.w;
        ys[r][c] = vy.x; ys[r][c + 1] = vy.y; ys[r][c + 2] = vy.z; ys[r][c + 3] = vy.w;
    }
    __syncthreads();
    int ti = t >> 5, tj = t & 31;
    float a0 = 0.f, a1 = 0.f, a2 = 0.f, a3 = 0.f;
    for (int d = 0; d < D_; ++d) {
        float yv = ys[tj][d];
        a0 += xs[ti][d] * yv;
        a1 += xs[ti + 8][d] * yv;
        a2 += xs[ti + 16][d] * yv;
        a3 += xs[ti + 24][d] * yv;
    }
    float ynj = yn[(size_t)b * N_ + jt * 32 + tj];
    float accs[4] = {a0, a1, a2, a3};
#pragma unroll
    for (int k = 0; k < 4; ++k) {
        int gi = it * 32 + ti + 8 * k;
        float sq = (xn[(size_t)b * M_ + gi] + ynj - 2.0f * accs[k]) * (1.0f / D_);
        float Dv = sqrtf(fmaxf(sq, 1e-12f));
        float kv = fminf(expf((SHIFT_ - Dv) * (1.0f / EPS_)), 448.0f);
        unsigned r8 = (unsigned)__builtin_amdgcn_cvt_pk_fp8_f32(kv, kv, 0, false);
        Kp[((size_t)b * M_ + gi) * N_ + jt * 32 + tj] = (unsigned char)(r8 & 0xff);
    }
}

// ---------------------------------------------------------------------------
// Persistent Sinkhorn — R3's proven zero-spill streaming structure, fp8 K.
// 1 WG (16 waves, 1024 thr) per batch; K streamed from L2 every iteration
// (256 KB/iter — half of R3's fp16 stream). No persistent K registers, no
// prefetch ring, no divergent load paths: live set ~56 < the 64-VGPR grant.
// Lane l: sub = l&15 owns scalar cols {sub*8 + 128c + e}; rg = l>>4.
// Wave w owns rows w*32 + g*4 + rg, g = 0..7 (4 rows in flight).
__global__ __attribute__((amdgpu_flat_work_group_size(1024, 1024)))
void wmd_sinkhorn(const unsigned char* __restrict__ K8, float* __restrict__ wmd) {
    int b = blockIdx.x;
    const unsigned char* Kb = K8 + (size_t)b * M_ * N_;
    __shared__ __half mrg[16][N_];   // per-wave fp16 column partials (16 KiB)
    __shared__ __half v_sh[N_];
    __shared__ float u_s[M_];
    __shared__ float wsum[16];
    int t = threadIdx.x, w = t >> 6, l = t & 63;
    int sub = l & 15, rg = l >> 4;
    const float pmarg = 1.0f / M_;
    const unsigned char* rbase = Kb + (size_t)(w * 32 + rg) * N_ + sub * 8;

    h2 vh[16];
    _Float16 one = (_Float16)1.0f;
#pragma unroll
    for (int j = 0; j < 16; ++j) vh[j] = (h2){one, one};  // v0 = 1

#pragma unroll 1
    for (int it = 0; it < NIT_; ++it) {
        h2 ca[16];
        _Float16 z = (_Float16)0.0f;
#pragma unroll
        for (int j = 0; j < 16; ++j) ca[j] = (h2){z, z};

#pragma unroll
        for (int g = 0; g < 8; ++g) {
            // 4 x uint2 = this row's 32 fp8 (cols sub*8 + 128c .. +8)
            const uint2* rp = (const uint2*)(rbase + (size_t)g * 4 * N_);
            uint2 kq0 = rp[0], kq1 = rp[16], kq2 = rp[32], kq3 = rp[48];
            float d0 = 0.f, d1 = 0.f, d2 = 0.f, d3 = 0.f;
            d0 = dot2f(cvt_h2<false>(kq0.x), vh[0],  d0);
            d1 = dot2f(cvt_h2<true>(kq0.x),  vh[1],  d1);
            d2 = dot2f(cvt_h2<false>(kq0.y), vh[2],  d2);
            d3 = dot2f(cvt_h2<true>(kq0.y),  vh[3],  d3);
            d0 = dot2f(cvt_h2<false>(kq1.x), vh[4],  d0);
            d1 = dot2f(cvt_h2<true>(kq1.x),  vh[5],  d1);
            d2 = dot2f(cvt_h2<false>(kq1.y), vh[6],  d2);
            d3 = dot2f(cvt_h2<true>(kq1.y),  vh[7],  d3);
            d0 = dot2f(cvt_h2<false>(kq2.x), vh[8],  d0);
            d1 = dot2f(cvt_h2<true>(kq2.x),  vh[9],  d1);
            d2 = dot2f(cvt_h2<false>(kq2.y), vh[10], d2);
            d3 = dot2f(cvt_h2<true>(kq2.y),  vh[11], d3);
            d0 = dot2f(cvt_h2<false>(kq3.x), vh[12], d0);
            d1 = dot2f(cvt_h2<true>(kq3.x),  vh[13], d1);
            d2 = dot2f(cvt_h2<false>(kq3.y), vh[14], d2);
            d3 = dot2f(cvt_h2<true>(kq3.y),  vh[15], d3);
            float dot = red16((d0 + d1) + (d2 + d3));
            float rd = __builtin_amdgcn_rcpf(dot);   // = 512*u
            if (sub == 0) u_s[w * 32 + g * 4 + rg] = rd;
            _Float16 uf = (_Float16)rd;
            h2 uh = (h2){uf, uf};
            ca[0]  = cvt_h2<false>(kq0.x) * uh + ca[0];
            ca[1]  = cvt_h2<true>(kq0.x)  * uh + ca[1];
            ca[2]  = cvt_h2<false>(kq0.y) * uh + ca[2];
            ca[3]  = cvt_h2<true>(kq0.y)  * uh + ca[3];
            ca[4]  = cvt_h2<false>(kq1.x) * uh + ca[4];
            ca[5]  = cvt_h2<true>(kq1.x)  * uh + ca[5];
            ca[6]  = cvt_h2<false>(kq1.y) * uh + ca[6];
            ca[7]  = cvt_h2<true>(kq1.y)  * uh + ca[7];
            ca[8]  = cvt_h2<false>(kq2.x) * uh + ca[8];
            ca[9]  = cvt_h2<true>(kq2.x)  * uh + ca[9];
            ca[10] = cvt_h2<false>(kq2.y) * uh + ca[10];
            ca[11] = cvt_h2<true>(kq2.y)  * uh + ca[11];
            ca[12] = cvt_h2<false>(kq3.x) * uh + ca[12];
            ca[13] = cvt_h2<true>(kq3.x)  * uh + ca[13];
            ca[14] = cvt_h2<false>(kq3.y) * uh + ca[14];
            ca[15] = cvt_h2<true>(kq3.y)  * uh + ca[15];
        }
        // merge the 4 rg-partials in-register (lanes xor 16, 32)
#pragma unroll
        for (int j = 0; j < 16; ++j) {
            ca[j] = ca[j] + u2h((unsigned)__shfl_xor((int)h2u(ca[j]), 16));
            ca[j] = ca[j] + u2h((unsigned)__shfl_xor((int)h2u(ca[j]), 32));
        }
        if (l < 16) {
#pragma unroll
            for (int c = 0; c < 4; ++c) {
                uint4 pk = {h2u(ca[4 * c]), h2u(ca[4 * c + 1]),
                            h2u(ca[4 * c + 2]), h2u(ca[4 * c + 3])};
                *(uint4*)&mrg[w][sub * 8 + 128 * c] = pk;
            }
        }
        __syncthreads();
        if (t < N_) {
            float s = 0.f;
#pragma unroll
            for (int ww = 0; ww < 16; ++ww) s += __half2float(mrg[ww][t]);
            v_sh[t] = __float2half_rn(__builtin_amdgcn_rcpf(s));  // v = rcp(colsum_scaled)
        }
        __syncthreads();
#pragma unroll
        for (int c = 0; c < 4; ++c) {
            uint4 vv = *(const uint4*)&v_sh[sub * 8 + 128 * c];
            vh[4 * c]     = u2h(vv.x);
            vh[4 * c + 1] = u2h(vv.y);
            vh[4 * c + 2] = u2h(vv.z);
            vh[4 * c + 3] = u2h(vv.w);
        }
    }

    // Final: wmd_b = sum_ij u_i K_ij v_j * D_ij, D_ij = SHIFT - EPS*ln(K_ij)
    float acc = 0.f;
#pragma unroll
    for (int g = 0; g < 8; ++g) {
        const uint2* rp = (const uint2*)(rbase + (size_t)g * 4 * N_);
        float us = u_s[w * 32 + g * 4 + rg];
#pragma unroll
        for (int c = 0; c < 4; ++c) {
            uint2 kq = rp[c * 16];
#pragma unroll
            for (int half = 0; half < 2; ++half) {
                unsigned word = half ? kq.y : kq.x;
                f2 klo = cvt_f2<false>(word);
                f2 khi = cvt_f2<true>(word);
                int jb = 4 * c + 2 * half;
                h2 v0 = vh[jb], v1 = vh[jb + 1];
                float kx = fmaxf(klo.x, 1e-9f), ky = fmaxf(klo.y, 1e-9f);
                acc += (us * kx * (float)v0.x) * (SHIFT_ - EPS_ * __logf(kx));
                acc += (us * ky * (float)v0.y) * (SHIFT_ - EPS_ * __logf(ky));
                kx = fmaxf(khi.x, 1e-9f); ky = fmaxf(khi.y, 1e-9f);
                acc += (us * kx * (float)v1.x) * (SHIFT_ - EPS_ * __logf(kx));
                acc += (us * ky * (float)v1.y) * (SHIFT_ - EPS_ * __logf(ky));
            }
        }
    }
#pragma unroll
    for (int off = 1; off < 64; off <<= 1) acc += __shfl_xor(acc, off);
    if (l == 0) wsum[w] = acc;
    __syncthreads();
    if (t == 0) {
        float s = 0.f;
#pragma unroll
        for (int ww = 0; ww < 16; ++ww) s += wsum[ww];
        wmd[b] = s * pmarg;
    }
}

// ---------------------------------------------------------------------------
__global__ void wmd_mse(const float* __restrict__ wmd, const float* __restrict__ labels,
                        float* __restrict__ out) {
    int l = threadIdx.x;
    float d = wmd[l] - labels[l];
    d = d * d;
#pragma unroll
    for (int off = 32; off; off >>= 1) d += __shfl_xor(d, off);
    if (l == 0) out[0] = d * (1.0f / B_);
}

// ---------------------------------------------------------------------------
extern "C" void kernel_launch(void* const* d_in, const int* in_sizes, int n_in,
                              void* d_out, int out_size, void* d_ws, size_t ws_size,
                              hipStream_t stream) {
    const float* x = (const float*)d_in[0];
    const float* y = (const float*)d_in[1];
    const float* labels = (const float*)d_in[2];
    float* out = (float*)d_out;

    char* ws = (char*)d_ws;
    unsigned char* K8 = (unsigned char*)ws;                             // 16 MiB
    size_t off = (size_t)B_ * M_ * N_;
    float* xn = (float*)(ws + off);        off += (size_t)B_ * M_ * sizeof(float);
    float* yn = (float*)(ws + off);        off += (size_t)B_ * N_ * sizeof(float);
    float* wmd = (float*)(ws + off);

    wmd_norms<<<(B_ * (M_ + N_)) / 4, 256, 0, stream>>>(x, y, xn, yn);
    wmd_build_k<<<dim3(N_ / 32, M_ / 32, B_), 256, 0, stream>>>(x, y, xn, yn, K8);
    wmd_sinkhorn<<<B_, 1024, 0, stream>>>(K8, wmd);
    wmd_mse<<<1, 64, 0, stream>>>(wmd, labels, out);
}

// Round 13
// 1791.589 us; speedup vs baseline: 1.4130x; 1.0656x over previous
//
#include <hip/hip_runtime.h>
#include <hip/hip_fp16.h>

#define B_ 64
#define M_ 512
#define N_ 512
#define D_ 128
constexpr float EPS_ = 0.05f;
constexpr float SHIFT_ = 1.25f;  // K' = exp((SHIFT - D)/EPS) fits fp8 e4m3 [~2e-3 .. 448]
constexpr int NIT_ = 200;

typedef _Float16 h2 __attribute__((ext_vector_type(2)));
typedef float f2 __attribute__((ext_vector_type(2)));

__device__ __forceinline__ unsigned h2u(h2 x) { return __builtin_bit_cast(unsigned, x); }
__device__ __forceinline__ h2 u2h(unsigned x) { return __builtin_bit_cast(h2, x); }

template <bool HI>
__device__ __forceinline__ h2 cvt_h2(unsigned w) {
#if __has_builtin(__builtin_amdgcn_cvt_scalef32_pk_f16_fp8)
    return __builtin_bit_cast(h2, __builtin_amdgcn_cvt_scalef32_pk_f16_fp8(w, 1.0f, HI));
#else
    f2 f = __builtin_amdgcn_cvt_pk_f32_fp8((int)w, HI);
    return __builtin_bit_cast(h2, __builtin_amdgcn_cvt_pkrtz(f.x, f.y));
#endif
}
template <bool HI>
__device__ __forceinline__ f2 cvt_f2(unsigned w) {
    return __builtin_amdgcn_cvt_pk_f32_fp8((int)w, HI);
}

__device__ __forceinline__ float dot2f(h2 a, h2 b, float c) {
#if __has_builtin(__builtin_amdgcn_fdot2)
    return __builtin_amdgcn_fdot2(a, b, c, false);
#else
    return fmaf((float)a.x, (float)b.x, fmaf((float)a.y, (float)b.y, c));
#endif
}

// sum across each 16-lane group via DPP, then across lane^16 via ds_swizzle:
// all 32 lanes of each half-wave get the 32-lane sum
__device__ __forceinline__ float red32(float x) {
    x += __builtin_bit_cast(float, __builtin_amdgcn_mov_dpp(__builtin_bit_cast(int, x), 0xB1, 0xF, 0xF, true));  // quad_perm xor1
    x += __builtin_bit_cast(float, __builtin_amdgcn_mov_dpp(__builtin_bit_cast(int, x), 0x4E, 0xF, 0xF, true));  // quad_perm xor2
    x += __builtin_bit_cast(float, __builtin_amdgcn_mov_dpp(__builtin_bit_cast(int, x), 0x124, 0xF, 0xF, true)); // row_ror:4
    x += __builtin_bit_cast(float, __builtin_amdgcn_mov_dpp(__builtin_bit_cast(int, x), 0x128, 0xF, 0xF, true)); // row_ror:8
    x += __builtin_bit_cast(float, __builtin_amdgcn_ds_swizzle(__builtin_bit_cast(int, x), 0x401F));             // xor16
    return x;
}

// ---------------------------------------------------------------------------
__global__ __launch_bounds__(256) void wmd_norms(const float* __restrict__ x,
                                                 const float* __restrict__ y,
                                                 float* __restrict__ xn,
                                                 float* __restrict__ yn) {
    int gw = (int)((blockIdx.x * blockDim.x + threadIdx.x) >> 6);
    int l = threadIdx.x & 63;
    const float* src; float* dst; int row;
    if (gw < B_ * M_) { src = x; dst = xn; row = gw; }
    else              { src = y; dst = yn; row = gw - B_ * M_; }
    float2 a = ((const float2*)(src + (size_t)row * D_))[l];
    float s = a.x * a.x + a.y * a.y;
#pragma unroll
    for (int off = 32; off; off >>= 1) s += __shfl_xor(s, off);
    if (l == 0) dst[row] = s;
}

// ---------------------------------------------------------------------------
// K'[b,i,j] = clamp(exp((SHIFT - D_ij)/EPS), 448) in fp8 e4m3 (contiguous)
__global__ __launch_bounds__(256) void wmd_build_k(const float* __restrict__ x,
                                                   const float* __restrict__ y,
                                                   const float* __restrict__ xn,
                                                   const float* __restrict__ yn,
                                                   unsigned char* __restrict__ Kp) {
    int b = blockIdx.z, it = blockIdx.y, jt = blockIdx.x;
    __shared__ float xs[32][129];
    __shared__ float ys[32][129];
    const float4* xb = (const float4*)(x + ((size_t)b * M_ + it * 32) * D_);
    const float4* yb = (const float4*)(y + ((size_t)b * N_ + jt * 32) * D_);
    int t = threadIdx.x;
#pragma unroll
    for (int k = 0; k < 4; ++k) {
        int idx = t + k * 256;
        int r = idx >> 5, c = (idx & 31) * 4;
        float4 vx = xb[idx];
        float4 vy = yb[idx];
        xs[r][c] = vx.x; xs[r][c + 1] = vx.y; xs[r][c + 2] = vx.z; xs[r][c + 3] = vx.w;
        ys[r][c] = vy.x; ys[r][c + 1] = vy.y; ys[r][c + 2] = vy.z; ys[r][c + 3] = vy.w;
    }
    __syncthreads();
    int ti = t >> 5, tj = t & 31;
    float a0 = 0.f, a1 = 0.f, a2 = 0.f, a3 = 0.f;
    for (int d = 0; d < D_; ++d) {
        float yv = ys[tj][d];
        a0 += xs[ti][d] * yv;
        a1 += xs[ti + 8][d] * yv;
        a2 += xs[ti + 16][d] * yv;
        a3 += xs[ti + 24][d] * yv;
    }
    float ynj = yn[(size_t)b * N_ + jt * 32 + tj];
    float accs[4] = {a0, a1, a2, a3};
#pragma unroll
    for (int k = 0; k < 4; ++k) {
        int gi = it * 32 + ti + 8 * k;
        float sq = (xn[(size_t)b * M_ + gi] + ynj - 2.0f * accs[k]) * (1.0f / D_);
        float Dv = sqrtf(fmaxf(sq, 1e-12f));
        float kv = fminf(expf((SHIFT_ - Dv) * (1.0f / EPS_)), 448.0f);
        unsigned r8 = (unsigned)__builtin_amdgcn_cvt_pk_fp8_f32(kv, kv, 0, false);
        Kp[((size_t)b * M_ + gi) * N_ + jt * 32 + tj] = (unsigned char)(r8 & 0xff);
    }
}

// ---------------------------------------------------------------------------
// Persistent Sinkhorn — fp8 L2-streaming, live set ~40 regs << 64-VGPR grant.
// 1 WG (16 waves, 1024 thr) per batch. Lane l: sub = l&31 owns cols
// [sub*16, +16) (ONE uint4 per row); rg = l>>5 -> 2 rows in flight per wave.
// Wave w owns rows w*32 + g*2 + rg, g = 0..15. fp8 converted ONCE per row
// (kh[8] reused by dot and ca). All reg arrays statically indexed; the two
// rg-dependent spots use cndmask-select, never runtime indexing.
__global__ __attribute__((amdgpu_flat_work_group_size(1024, 1024)))
void wmd_sinkhorn(const unsigned char* __restrict__ K8, float* __restrict__ wmd) {
    int b = blockIdx.x;
    const unsigned char* Kb = K8 + (size_t)b * M_ * N_;
    __shared__ __half mrg[16][N_];   // per-wave fp16 column partials (16 KiB)
    __shared__ __half v_sh[N_];
    __shared__ float u_s[M_];
    __shared__ float wsum[16];
    int t = threadIdx.x, w = t >> 6, l = t & 63;
    int sub = l & 31, rg = l >> 5;
    const float pmarg = 1.0f / M_;
    const unsigned char* rbase = Kb + (size_t)(w * 32 + rg) * N_ + sub * 16;

    h2 vh[8];
    _Float16 one = (_Float16)1.0f;
#pragma unroll
    for (int j = 0; j < 8; ++j) vh[j] = (h2){one, one};  // v0 = 1

#pragma unroll 1
    for (int it = 0; it < NIT_; ++it) {
        h2 ca[8];
        _Float16 z = (_Float16)0.0f;
#pragma unroll
        for (int j = 0; j < 8; ++j) ca[j] = (h2){z, z};

#pragma unroll
        for (int g = 0; g < 16; ++g) {
            uint4 kq = *(const uint4*)(rbase + (size_t)g * 2 * N_);
            h2 kh[8];
            kh[0] = cvt_h2<false>(kq.x); kh[1] = cvt_h2<true>(kq.x);
            kh[2] = cvt_h2<false>(kq.y); kh[3] = cvt_h2<true>(kq.y);
            kh[4] = cvt_h2<false>(kq.z); kh[5] = cvt_h2<true>(kq.z);
            kh[6] = cvt_h2<false>(kq.w); kh[7] = cvt_h2<true>(kq.w);
            float d0 = 0.f, d1 = 0.f, d2 = 0.f, d3 = 0.f;
            d0 = dot2f(kh[0], vh[0], d0);
            d1 = dot2f(kh[1], vh[1], d1);
            d2 = dot2f(kh[2], vh[2], d2);
            d3 = dot2f(kh[3], vh[3], d3);
            d0 = dot2f(kh[4], vh[4], d0);
            d1 = dot2f(kh[5], vh[5], d1);
            d2 = dot2f(kh[6], vh[6], d2);
            d3 = dot2f(kh[7], vh[7], d3);
            float dot = red32((d0 + d1) + (d2 + d3));
            float rd = __builtin_amdgcn_rcpf(dot);   // = 512*u (scaled u, fp16 mid-range)
            if (sub == 0) u_s[w * 32 + g * 2 + rg] = rd;
            _Float16 uf = (_Float16)rd;
            h2 uh = (h2){uf, uf};
            ca[0] = kh[0] * uh + ca[0];
            ca[1] = kh[1] * uh + ca[1];
            ca[2] = kh[2] * uh + ca[2];
            ca[3] = kh[3] * uh + ca[3];
            ca[4] = kh[4] * uh + ca[4];
            ca[5] = kh[5] * uh + ca[5];
            ca[6] = kh[6] * uh + ca[6];
            ca[7] = kh[7] * uh + ca[7];
        }
        // merge the two rg-halves (same columns): lanes xor 32
#pragma unroll
        for (int j = 0; j < 8; ++j)
            ca[j] = ca[j] + u2h((unsigned)__shfl_xor((int)h2u(ca[j]), 32));
        // write wave partial: lane l writes the uint4 for cols sub*16 + rg*8..+8
        {
            uint4 lo = {h2u(ca[0]), h2u(ca[1]), h2u(ca[2]), h2u(ca[3])};
            uint4 hi = {h2u(ca[4]), h2u(ca[5]), h2u(ca[6]), h2u(ca[7])};
            uint4 pk = rg ? hi : lo;                 // cndmask, no runtime indexing
            *(uint4*)&mrg[w][sub * 16 + rg * 8] = pk;  // 64 lanes -> contiguous 1 KiB
        }
        __syncthreads();
        if (t < N_) {
            float s = 0.f;
#pragma unroll
            for (int ww = 0; ww < 16; ++ww) s += __half2float(mrg[ww][t]);
            v_sh[t] = __float2half_rn(__builtin_amdgcn_rcpf(s));  // v = rcp(colsum_scaled)
        }
        __syncthreads();
        // reload vh: own half via contiguous b128, other half via shfl_xor(32)
        {
            uint4 own = *(const uint4*)&v_sh[sub * 16 + rg * 8];
            uint4 oth;
            oth.x = (unsigned)__shfl_xor((int)own.x, 32);
            oth.y = (unsigned)__shfl_xor((int)own.y, 32);
            oth.z = (unsigned)__shfl_xor((int)own.z, 32);
            oth.w = (unsigned)__shfl_xor((int)own.w, 32);
            uint4 vlo = rg ? oth : own;   // cols sub*16 .. +8
            uint4 vhi = rg ? own : oth;   // cols sub*16+8 .. +16
            vh[0] = u2h(vlo.x); vh[1] = u2h(vlo.y); vh[2] = u2h(vlo.z); vh[3] = u2h(vlo.w);
            vh[4] = u2h(vhi.x); vh[5] = u2h(vhi.y); vh[6] = u2h(vhi.z); vh[7] = u2h(vhi.w);
        }
    }

    // Final: wmd_b = sum_ij u_i K_ij v_j * D_ij, D_ij = SHIFT - EPS*ln(K_ij)
    float acc = 0.f;
#pragma unroll
    for (int g = 0; g < 16; ++g) {
        uint4 kq = *(const uint4*)(rbase + (size_t)g * 2 * N_);
        float us = u_s[w * 32 + g * 2 + rg];
        const unsigned dw[4] = {kq.x, kq.y, kq.z, kq.w};
#pragma unroll
        for (int dd = 0; dd < 4; ++dd) {
            f2 klo = cvt_f2<false>(dw[dd]);
            f2 khi = cvt_f2<true>(dw[dd]);
            h2 v0 = vh[2 * dd], v1 = vh[2 * dd + 1];
            float kx = fmaxf(klo.x, 1e-9f), ky = fmaxf(klo.y, 1e-9f);
            acc += (us * kx * (float)v0.x) * (SHIFT_ - EPS_ * __logf(kx));
            acc += (us * ky * (float)v0.y) * (SHIFT_ - EPS_ * __logf(ky));
            kx = fmaxf(khi.x, 1e-9f); ky = fmaxf(khi.y, 1e-9f);
            acc += (us * kx * (float)v1.x) * (SHIFT_ - EPS_ * __logf(kx));
            acc += (us * ky * (float)v1.y) * (SHIFT_ - EPS_ * __logf(ky));
        }
    }
#pragma unroll
    for (int off = 1; off < 64; off <<= 1) acc += __shfl_xor(acc, off);
    if (l == 0) wsum[w] = acc;
    __syncthreads();
    if (t == 0) {
        float s = 0.f;
#pragma unroll
        for (int ww = 0; ww < 16; ++ww) s += wsum[ww];
        wmd[b] = s * pmarg;
    }
}

// ---------------------------------------------------------------------------
__global__ void wmd_mse(const float* __restrict__ wmd, const float* __restrict__ labels,
                        float* __restrict__ out) {
    int l = threadIdx.x;
    float d = wmd[l] - labels[l];
    d = d * d;
#pragma unroll
    for (int off = 32; off; off >>= 1) d += __shfl_xor(d, off);
    if (l == 0) out[0] = d * (1.0f / B_);
}

// ---------------------------------------------------------------------------
extern "C" void kernel_launch(void* const* d_in, const int* in_sizes, int n_in,
                              void* d_out, int out_size, void* d_ws, size_t ws_size,
                              hipStream_t stream) {
    const float* x = (const float*)d_in[0];
    const float* y = (const float*)d_in[1];
    const float* labels = (const float*)d_in[2];
    float* out = (float*)d_out;

    char* ws = (char*)d_ws;
    unsigned char* K8 = (unsigned char*)ws;                             // 16 MiB
    size_t off = (size_t)B_ * M_ * N_;
    float* xn = (float*)(ws + off);        off += (size_t)B_ * M_ * sizeof(float);
    float* yn = (float*)(ws + off);        off += (size_t)B_ * N_ * sizeof(float);
    float* wmd = (float*)(ws + off);

    wmd_norms<<<(B_ * (M_ + N_)) / 4, 256, 0, stream>>>(x, y, xn, yn);
    wmd_build_k<<<dim3(N_ / 32, M_ / 32, B_), 256, 0, stream>>>(x, y, xn, yn, K8);
    wmd_sinkhorn<<<B_, 1024, 0, stream>>>(K8, wmd);
    wmd_mse<<<1, 64, 0, stream>>>(wmd, labels, out);
}